// Round 4
// baseline (407.045 us; speedup 1.0000x reference)
//
#include <hip/hip_runtime.h>
#include <hip/hip_bf16.h>

// Problem constants (match reference)
constexpr int cB  = 8;
constexpr int cS  = 4096;
constexpr int cH  = 768;
constexpr int cNH = 12;
constexpr int cL  = 2;
constexpr int cNS = 64;
constexpr int cDH = 64;
constexpr int cM  = cB * cNS;  // 512 rows of activations

typedef __attribute__((ext_vector_type(8))) short bf16x8;
typedef __attribute__((ext_vector_type(4))) float f32x4;
typedef __attribute__((ext_vector_type(4))) unsigned short u16x4;

__device__ __forceinline__ float b2f(unsigned short u) {
    union { float f; unsigned int i; } x; x.i = (unsigned int)u << 16; return x.f;
}
__device__ __forceinline__ unsigned short f2b(float f) {
    __hip_bfloat16 h = __float2bfloat16(f);
    return *(unsigned short*)&h;
}

// ---------------------------------------------------------------------------
// 1) Fused prep (512 threads/block): blocks [0, 512) segment-mean pooling;
//    blocks [512, 1088) weight transpose+convert, 2 tiles/block.
//    (byte-identical to the verified 285 us baseline)
// ---------------------------------------------------------------------------
union PrepShared {
    struct { int cnt; int list[cS]; float ps[192][4]; } p;   // 19.5 KB
    float T[2][64][65];                                      // 33.3 KB
};

__global__ __launch_bounds__(512) void prep_kernel(
    const int* __restrict__ sent_ind, const float* __restrict__ sl,
    __hip_bfloat16* __restrict__ xb,
    const float* __restrict__ Wq, const float* __restrict__ Wk,
    const float* __restrict__ Wv, const float* __restrict__ Wo,
    __hip_bfloat16* __restrict__ wt)
{
    __shared__ PrepShared sh;
    int tid = threadIdx.x;

    if (blockIdx.x < (unsigned)cM) {
        // ---------------- pool ----------------
        int bn = blockIdx.x;
        int b = bn >> 6, n = bn & (cNS - 1);
        if (tid == 0) sh.p.cnt = 0;
        __syncthreads();
        const int* si = sent_ind + (size_t)b * cS;
        for (int s = tid; s < cS; s += 512)
            if (s != 0 && si[s] == n) { int p = atomicAdd(&sh.p.cnt, 1); sh.p.list[p] = s; }
        __syncthreads();
        int c = sh.p.cnt;
        int grp = tid >> 8;          // 0 or 1: row-group
        int t   = tid & 255;
        int c0 = c >> 1;
        int lo = grp ? c0 : 0;
        int hi = grp ? c  : c0;
        float s0 = 0.f, s1 = 0.f, s2 = 0.f, s3 = 0.f;
        if (t < 192) {
            const float* bbase = sl + (size_t)b * cS * cH;
            int col = t * 4;
            float4 a0 = {0.f, 0.f, 0.f, 0.f};
            float4 a1 = {0.f, 0.f, 0.f, 0.f};
            float4 a2 = {0.f, 0.f, 0.f, 0.f};
            float4 a3 = {0.f, 0.f, 0.f, 0.f};
            int i = lo;
            for (; i + 4 <= hi; i += 4) {
                float4 r0 = *(const float4*)(bbase + (size_t)sh.p.list[i + 0] * cH + col);
                float4 r1 = *(const float4*)(bbase + (size_t)sh.p.list[i + 1] * cH + col);
                float4 r2 = *(const float4*)(bbase + (size_t)sh.p.list[i + 2] * cH + col);
                float4 r3 = *(const float4*)(bbase + (size_t)sh.p.list[i + 3] * cH + col);
                a0.x += r0.x; a0.y += r0.y; a0.z += r0.z; a0.w += r0.w;
                a1.x += r1.x; a1.y += r1.y; a1.z += r1.z; a1.w += r1.w;
                a2.x += r2.x; a2.y += r2.y; a2.z += r2.z; a2.w += r2.w;
                a3.x += r3.x; a3.y += r3.y; a3.z += r3.z; a3.w += r3.w;
            }
            for (; i < hi; ++i) {
                float4 r0 = *(const float4*)(bbase + (size_t)sh.p.list[i] * cH + col);
                a0.x += r0.x; a0.y += r0.y; a0.z += r0.z; a0.w += r0.w;
            }
            s0 = a0.x + a1.x + a2.x + a3.x;
            s1 = a0.y + a1.y + a2.y + a3.y;
            s2 = a0.z + a1.z + a2.z + a3.z;
            s3 = a0.w + a1.w + a2.w + a3.w;
        }
        if (grp == 1 && t < 192) {
            sh.p.ps[t][0] = s0; sh.p.ps[t][1] = s1;
            sh.p.ps[t][2] = s2; sh.p.ps[t][3] = s3;
        }
        __syncthreads();
        if (grp == 0 && t < 192) {
            float inv = 1.0f / (float)c;
            __hip_bfloat16* xr = xb + (size_t)bn * cH + t * 4;
            xr[0] = __float2bfloat16((s0 + sh.p.ps[t][0]) * inv);
            xr[1] = __float2bfloat16((s1 + sh.p.ps[t][1]) * inv);
            xr[2] = __float2bfloat16((s2 + sh.p.ps[t][2]) * inv);
            xr[3] = __float2bfloat16((s3 + sh.p.ps[t][3]) * inv);
        }
    } else {
        // ---------------- wconv: 2 tiles per block ----------------
        int sub = tid >> 8;                         // which tile
        int t   = tid & 255;
        int bi = (blockIdx.x - cM) * 2 + sub;       // 0..1151 = (12 x 12 x 8)
        int bx = bi % 12, by = (bi / 12) % 12, mat = bi / 144;
        int layer = mat >> 2, which = mat & 3;
        const float* W = (which == 0 ? Wq : which == 1 ? Wk : which == 2 ? Wv : Wo)
                         + (size_t)layer * cH * cH;
        int k0 = by * 64, n0 = bx * 64;
        int r = t >> 2, cb = (t & 3) * 16;
        #pragma unroll
        for (int u = 0; u < 4; ++u) {
            float4 w4 = *(const float4*)(W + (size_t)(k0 + r) * cH + n0 + cb + u * 4);
            sh.T[sub][r][cb + u * 4 + 0] = w4.x; sh.T[sub][r][cb + u * 4 + 1] = w4.y;
            sh.T[sub][r][cb + u * 4 + 2] = w4.z; sh.T[sub][r][cb + u * 4 + 3] = w4.w;
        }
        __syncthreads();
        // lane writes 16 bf16 = 32 B contiguous (two 16-B stores)
        int nn = t >> 2, kseg = (t & 3) * 16;
        __hip_bfloat16 tmp[16] __attribute__((aligned(16)));
        #pragma unroll
        for (int j = 0; j < 16; ++j)
            tmp[j] = __float2bfloat16(sh.T[sub][kseg + j][nn]);
        __hip_bfloat16* dst = wt + ((size_t)mat * cH + n0 + nn) * cH + k0 + kseg;
        *(bf16x8*)(dst)     = *(const bf16x8*)(tmp);
        *(bf16x8*)(dst + 8) = *(const bf16x8*)(tmp + 8);
    }
}

// ---------------------------------------------------------------------------
// 2) Fused qkv-GEMM + attention.  One block per (batch, head) = 96 blocks.
//    (byte-identical to the verified 285 us baseline)
// ---------------------------------------------------------------------------
struct AttnShared {
    float QP[cNS][cDH + 4];  // Q, later overlaid by P
    float Ks[cNS][cDH + 4];
    float Vt[cDH][cNS + 4];
};

__global__ __launch_bounds__(256) void qkvattn_kernel(
    const __hip_bfloat16* __restrict__ x_bf,
    const __hip_bfloat16* __restrict__ wqkv,   // [3][H][H] bf16 (n-major)
    const float* __restrict__ bq, const float* __restrict__ bk,
    const float* __restrict__ bv,
    __hip_bfloat16* __restrict__ ctx_bf)
{
    __shared__ AttnShared sh;
    int tid = threadIdx.x;
    int lane = tid & 63, wave = tid >> 6;
    int l15 = lane & 15, q4 = lane >> 4;
    int b = blockIdx.x / cNH, hh = blockIdx.x % cNH;

    const __hip_bfloat16* Arow[4];
    #pragma unroll
    for (int m = 0; m < 4; ++m)
        Arow[m] = x_bf + (size_t)(b * 64 + m * 16 + l15) * cH + q4 * 8;
    const __hip_bfloat16* Brow[3];
    int cmat[3], cnt_[3];
    #pragma unroll
    for (int j = 0; j < 3; ++j) {
        int c = wave * 3 + j;
        cmat[j] = c >> 2; cnt_[j] = c & 3;
        Brow[j] = wqkv + (size_t)cmat[j] * cH * cH
                       + (size_t)(hh * 64 + cnt_[j] * 16 + l15) * cH + q4 * 8;
    }

    f32x4 acc[3][4];
    #pragma unroll
    for (int j = 0; j < 3; ++j)
        #pragma unroll
        for (int m = 0; m < 4; ++m) acc[j][m] = (f32x4){0.f, 0.f, 0.f, 0.f};

    #pragma unroll 4
    for (int k0 = 0; k0 < cH; k0 += 32) {
        bf16x8 a[4], bb8[3];
        #pragma unroll
        for (int m = 0; m < 4; ++m) a[m] = *(const bf16x8*)(Arow[m] + k0);
        #pragma unroll
        for (int j = 0; j < 3; ++j) bb8[j] = *(const bf16x8*)(Brow[j] + k0);
        #pragma unroll
        for (int j = 0; j < 3; ++j)
            #pragma unroll
            for (int m = 0; m < 4; ++m)
                acc[j][m] = __builtin_amdgcn_mfma_f32_16x16x32_bf16(a[m], bb8[j], acc[j][m], 0, 0, 0);
    }

    const float scale = 0.125f;  // 1/sqrt(64)
    #pragma unroll
    for (int j = 0; j < 3; ++j) {
        int mat = cmat[j], nt = cnt_[j];
        int col_d = nt * 16 + l15;
        int col_g = hh * 64 + col_d;
        float bias = (mat == 0 ? bq : mat == 1 ? bk : bv)[col_g];
        #pragma unroll
        for (int m = 0; m < 4; ++m) {
            #pragma unroll
            for (int r = 0; r < 4; ++r) {
                int row_s = m * 16 + q4 * 4 + r;
                float v = acc[j][m][r] + bias;
                if (mat == 0)      sh.QP[row_s][col_d] = v * scale;
                else if (mat == 1) sh.Ks[row_s][col_d] = v;
                else               sh.Vt[col_d][row_s] = v;
            }
        }
    }
    __syncthreads();

    int tx = tid & 15, ty = tid >> 4;  // 16x16 threads, 4x4 microtiles
    float accs[4][4] = {};
    for (int d = 0; d < cDH; d += 4) {
        float4 qv[4], kv[4];
        #pragma unroll
        for (int i = 0; i < 4; ++i) qv[i] = *(const float4*)&sh.QP[ty * 4 + i][d];
        #pragma unroll
        for (int j = 0; j < 4; ++j) kv[j] = *(const float4*)&sh.Ks[tx + j * 16][d];
        #pragma unroll
        for (int i = 0; i < 4; ++i)
            #pragma unroll
            for (int j = 0; j < 4; ++j)
                accs[i][j] += qv[i].x * kv[j].x + qv[i].y * kv[j].y +
                              qv[i].z * kv[j].z + qv[i].w * kv[j].w;
    }
    __syncthreads();   // all QK^T reads done before P overlays Q
    #pragma unroll
    for (int i = 0; i < 4; ++i)
        #pragma unroll
        for (int j = 0; j < 4; ++j)
            sh.QP[ty * 4 + i][tx + j * 16] = accs[i][j];
    __syncthreads();

    {   // softmax: row = tid>>2, 16 cols/thread, quad shuffle
        int row = tid >> 2, jq = tid & 3;
        float e[16];
        float m = -1e30f;
        #pragma unroll
        for (int c = 0; c < 16; ++c) { e[c] = sh.QP[row][jq * 16 + c]; m = fmaxf(m, e[c]); }
        m = fmaxf(m, __shfl_xor(m, 1));
        m = fmaxf(m, __shfl_xor(m, 2));
        float s = 0.f;
        #pragma unroll
        for (int c = 0; c < 16; ++c) { e[c] = __expf(e[c] - m); s += e[c]; }
        s += __shfl_xor(s, 1);
        s += __shfl_xor(s, 2);
        float inv = 1.0f / s;
        #pragma unroll
        for (int c = 0; c < 16; ++c) sh.QP[row][jq * 16 + c] = e[c] * inv;
    }
    __syncthreads();

    float acco[4][4] = {};
    for (int c = 0; c < cNS; c += 4) {
        float4 p4[4], vt4[4];
        #pragma unroll
        for (int i = 0; i < 4; ++i) p4[i] = *(const float4*)&sh.QP[ty * 4 + i][c];
        #pragma unroll
        for (int j = 0; j < 4; ++j) vt4[j] = *(const float4*)&sh.Vt[tx + j * 16][c];
        #pragma unroll
        for (int i = 0; i < 4; ++i)
            #pragma unroll
            for (int j = 0; j < 4; ++j)
                acco[i][j] += p4[i].x * vt4[j].x + p4[i].y * vt4[j].y +
                              p4[i].z * vt4[j].z + p4[i].w * vt4[j].w;
    }
    size_t base = ((size_t)b * cNS) * cH + hh * cDH;
    #pragma unroll
    for (int i = 0; i < 4; ++i)
        #pragma unroll
        for (int j = 0; j < 4; ++j)
            ctx_bf[base + (size_t)(ty * 4 + i) * cH + tx + j * 16] =
                __float2bfloat16(acco[i][j]);
}

// ---------------------------------------------------------------------------
// 3) O-GEMM + bias + GELU + in-block LayerNorm.  Grid = 16 blocks x 512 thr.
//    Each block owns 32 COMPLETE rows (32 x 768): the LN dependency is
//    block-local, so no fence / no extra dispatch. h lives only in LDS
//    (never touches HBM). 8 waves: wave w -> m-sub (w&1, 16 rows),
//    n-range (w>>1)*192 (12 MFMA col-tiles). Wt re-read 16x but L3-resident
//    (1.18 MB). Removes both ln dispatches AND both ogemm->ln boundaries.
// ---------------------------------------------------------------------------
__global__ __launch_bounds__(512) void ogemm_ln_kernel(
    const __hip_bfloat16* __restrict__ A,      // ctx_bf [M][H]
    const __hip_bfloat16* __restrict__ Wt,     // [H][H] n-major
    const float* __restrict__ bias,
    const float* __restrict__ g, const float* __restrict__ bb,
    __hip_bfloat16* __restrict__ xb,           // LN out bf16 [M][H]
    float* __restrict__ outf)                  // LN out f32 (last layer) or null
{
    __shared__ unsigned short hs[32][776];     // h tile (bf16 bits), 48.5 KB
    int tid  = threadIdx.x;
    int lane = tid & 63;
    int wave = tid >> 6;
    int l15 = lane & 15, q4 = lane >> 4;
    int msub = wave & 1;
    int nb   = (wave >> 1) * 192;
    int r0 = blockIdx.x * 32;
    int m0 = r0 + msub * 16;

    const __hip_bfloat16* Arow = A  + (size_t)(m0 + l15) * cH + q4 * 8;
    const __hip_bfloat16* Wr   = Wt + (size_t)(nb + l15) * cH + q4 * 8;

    f32x4 acc[12];
    #pragma unroll
    for (int j = 0; j < 12; ++j) acc[j] = (f32x4){0.f, 0.f, 0.f, 0.f};

    #pragma unroll 2
    for (int k0 = 0; k0 < cH; k0 += 32) {
        bf16x8 a = *(const bf16x8*)(Arow + k0);
        bf16x8 bw[12];
        #pragma unroll
        for (int j = 0; j < 12; ++j)
            bw[j] = *(const bf16x8*)(Wr + (size_t)j * 16 * cH + k0);
        #pragma unroll
        for (int j = 0; j < 12; ++j)
            acc[j] = __builtin_amdgcn_mfma_f32_16x16x32_bf16(a, bw[j], acc[j], 0, 0, 0);
    }

    // bias + GELU -> LDS (bf16 bits, matching baseline's bf16 h numerics)
    #pragma unroll
    for (int j = 0; j < 12; ++j) {
        int col = nb + j * 16 + l15;
        float bv = bias[col];
        #pragma unroll
        for (int r = 0; r < 4; ++r) {
            float v = acc[j][r] + bv;
            v = 0.5f * v * (1.0f + erff(v * 0.70710678118654752f));
            hs[msub * 16 + q4 * 4 + r][col] = f2b(v);
        }
    }
    __syncthreads();

    // ---- in-block LN: wave handles rows wave*4 .. wave*4+4, 12 elems/lane --
    float gv[12], bv2[12];
    {
        const float* gp = g  + lane * 12;
        const float* bp = bb + lane * 12;
        #pragma unroll
        for (int j = 0; j < 3; ++j) {
            float4 g4 = *(const float4*)(gp + j * 4);
            float4 b4 = *(const float4*)(bp + j * 4);
            gv[j * 4 + 0] = g4.x; gv[j * 4 + 1] = g4.y;
            gv[j * 4 + 2] = g4.z; gv[j * 4 + 3] = g4.w;
            bv2[j * 4 + 0] = b4.x; bv2[j * 4 + 1] = b4.y;
            bv2[j * 4 + 2] = b4.z; bv2[j * 4 + 3] = b4.w;
        }
    }
    #pragma unroll
    for (int rr = 0; rr < 4; ++rr) {
        int lrow = wave * 4 + rr;
        int grow = r0 + lrow;
        const unsigned short* hr = &hs[lrow][lane * 12];
        float v[12];
        #pragma unroll
        for (int j = 0; j < 3; ++j) {
            u16x4 q = *(const u16x4*)(hr + j * 4);
            v[j * 4 + 0] = b2f(q[0]); v[j * 4 + 1] = b2f(q[1]);
            v[j * 4 + 2] = b2f(q[2]); v[j * 4 + 3] = b2f(q[3]);
        }
        float s = 0.f;
        #pragma unroll
        for (int j = 0; j < 12; ++j) s += v[j];
        #pragma unroll
        for (int o = 32; o; o >>= 1) s += __shfl_xor(s, o);
        float mu = s * (1.0f / 768.0f);
        float ss = 0.f;
        #pragma unroll
        for (int j = 0; j < 12; ++j) { v[j] -= mu; ss += v[j] * v[j]; }
        #pragma unroll
        for (int o = 32; o; o >>= 1) ss += __shfl_xor(ss, o);
        float var = ss * (1.0f / 768.0f);
        float inv = rsqrtf(var + 1e-12f);
        float o12[12];
        #pragma unroll
        for (int j = 0; j < 12; ++j) o12[j] = v[j] * inv * gv[j] + bv2[j];

        unsigned short* xr = (unsigned short*)(xb + (size_t)grow * cH) + lane * 12;
        #pragma unroll
        for (int j = 0; j < 3; ++j) {
            u16x4 q;
            q[0] = f2b(o12[j * 4 + 0]); q[1] = f2b(o12[j * 4 + 1]);
            q[2] = f2b(o12[j * 4 + 2]); q[3] = f2b(o12[j * 4 + 3]);
            *(u16x4*)(xr + j * 4) = q;
        }
        if (outf) {
            float* orow = outf + (size_t)grow * cH + lane * 12;
            #pragma unroll
            for (int j = 0; j < 3; ++j) {
                float4 o4 = { o12[j * 4 + 0], o12[j * 4 + 1],
                              o12[j * 4 + 2], o12[j * 4 + 3] };
                *(float4*)(orow + j * 4) = o4;
            }
        }
    }
}

// ---------------------------------------------------------------------------
extern "C" void kernel_launch(void* const* d_in, const int* in_sizes, int n_in,
                              void* d_out, int out_size, void* d_ws, size_t ws_size,
                              hipStream_t stream) {
    const int*   sent_ind = (const int*)d_in[0];
    const float* start    = (const float*)d_in[1];
    const float* Wq = (const float*)d_in[2];
    const float* bq = (const float*)d_in[3];
    const float* Wk = (const float*)d_in[4];
    const float* bk = (const float*)d_in[5];
    const float* Wv = (const float*)d_in[6];
    const float* bv = (const float*)d_in[7];
    const float* Wo = (const float*)d_in[8];
    const float* bo = (const float*)d_in[9];
    const float* ln_g = (const float*)d_in[10];
    const float* ln_b = (const float*)d_in[11];
    float* out = (float*)d_out;

    char* w = (char*)d_ws;
    __hip_bfloat16* wt     = (__hip_bfloat16*)w;                          // 8*H*H bf16
    __hip_bfloat16* x_bf   = (__hip_bfloat16*)(w + 9437184);              // M*H bf16
    __hip_bfloat16* ctx_bf = (__hip_bfloat16*)(w + 9437184 + 786432);     // M*H bf16

    prep_kernel<<<cM + 576, 512, 0, stream>>>(sent_ind, start, x_bf,
                                              Wq, Wk, Wv, Wo, wt);

    for (int i = 0; i < cL; ++i) {
        const __hip_bfloat16* wqkv = wt + (size_t)(i * 4) * cH * cH;     // q,k,v contiguous
        const __hip_bfloat16* wto  = wt + (size_t)(i * 4 + 3) * cH * cH;
        qkvattn_kernel<<<cB * cNH, 256, 0, stream>>>(
            x_bf, wqkv, bq + (size_t)i * cH, bk + (size_t)i * cH, bv + (size_t)i * cH,
            ctx_bf);
        ogemm_ln_kernel<<<16, 512, 0, stream>>>(
            ctx_bf, wto, bo + (size_t)i * cH,
            ln_g + (size_t)i * cH, ln_b + (size_t)i * cH,
            x_bf, (i == cL - 1) ? out : nullptr);
    }
}

// Round 5
// 336.053 us; speedup vs baseline: 1.2113x; 1.2113x over previous
//
#include <hip/hip_runtime.h>
#include <hip/hip_bf16.h>

// Problem constants (match reference)
constexpr int cB  = 8;
constexpr int cS  = 4096;
constexpr int cH  = 768;
constexpr int cNH = 12;
constexpr int cL  = 2;
constexpr int cNS = 64;
constexpr int cDH = 64;
constexpr int cM  = cB * cNS;  // 512 rows of activations

typedef __attribute__((ext_vector_type(8))) short bf16x8;
typedef __attribute__((ext_vector_type(4))) float f32x4;
typedef __attribute__((ext_vector_type(4))) unsigned short u16x4;

__device__ __forceinline__ float b2f(unsigned short u) {
    union { float f; unsigned int i; } x; x.i = (unsigned int)u << 16; return x.f;
}
__device__ __forceinline__ unsigned short f2b(float f) {
    __hip_bfloat16 h = __float2bfloat16(f);
    return *(unsigned short*)&h;
}

// ---------------------------------------------------------------------------
// 1) Fused prep (512 threads/block): blocks [0, 512) segment-mean pooling;
//    blocks [512, 1088) weight transpose+convert, 2 tiles/block.
//    (byte-identical to the verified 285 us baseline)
// ---------------------------------------------------------------------------
union PrepShared {
    struct { int cnt; int list[cS]; float ps[192][4]; } p;   // 19.5 KB
    float T[2][64][65];                                      // 33.3 KB
};

__global__ __launch_bounds__(512) void prep_kernel(
    const int* __restrict__ sent_ind, const float* __restrict__ sl,
    __hip_bfloat16* __restrict__ xb,
    const float* __restrict__ Wq, const float* __restrict__ Wk,
    const float* __restrict__ Wv, const float* __restrict__ Wo,
    __hip_bfloat16* __restrict__ wt)
{
    __shared__ PrepShared sh;
    int tid = threadIdx.x;

    if (blockIdx.x < (unsigned)cM) {
        // ---------------- pool ----------------
        int bn = blockIdx.x;
        int b = bn >> 6, n = bn & (cNS - 1);
        if (tid == 0) sh.p.cnt = 0;
        __syncthreads();
        const int* si = sent_ind + (size_t)b * cS;
        for (int s = tid; s < cS; s += 512)
            if (s != 0 && si[s] == n) { int p = atomicAdd(&sh.p.cnt, 1); sh.p.list[p] = s; }
        __syncthreads();
        int c = sh.p.cnt;
        int grp = tid >> 8;          // 0 or 1: row-group
        int t   = tid & 255;
        int c0 = c >> 1;
        int lo = grp ? c0 : 0;
        int hi = grp ? c  : c0;
        float s0 = 0.f, s1 = 0.f, s2 = 0.f, s3 = 0.f;
        if (t < 192) {
            const float* bbase = sl + (size_t)b * cS * cH;
            int col = t * 4;
            float4 a0 = {0.f, 0.f, 0.f, 0.f};
            float4 a1 = {0.f, 0.f, 0.f, 0.f};
            float4 a2 = {0.f, 0.f, 0.f, 0.f};
            float4 a3 = {0.f, 0.f, 0.f, 0.f};
            int i = lo;
            for (; i + 4 <= hi; i += 4) {
                float4 r0 = *(const float4*)(bbase + (size_t)sh.p.list[i + 0] * cH + col);
                float4 r1 = *(const float4*)(bbase + (size_t)sh.p.list[i + 1] * cH + col);
                float4 r2 = *(const float4*)(bbase + (size_t)sh.p.list[i + 2] * cH + col);
                float4 r3 = *(const float4*)(bbase + (size_t)sh.p.list[i + 3] * cH + col);
                a0.x += r0.x; a0.y += r0.y; a0.z += r0.z; a0.w += r0.w;
                a1.x += r1.x; a1.y += r1.y; a1.z += r1.z; a1.w += r1.w;
                a2.x += r2.x; a2.y += r2.y; a2.z += r2.z; a2.w += r2.w;
                a3.x += r3.x; a3.y += r3.y; a3.z += r3.z; a3.w += r3.w;
            }
            for (; i < hi; ++i) {
                float4 r0 = *(const float4*)(bbase + (size_t)sh.p.list[i] * cH + col);
                a0.x += r0.x; a0.y += r0.y; a0.z += r0.z; a0.w += r0.w;
            }
            s0 = a0.x + a1.x + a2.x + a3.x;
            s1 = a0.y + a1.y + a2.y + a3.y;
            s2 = a0.z + a1.z + a2.z + a3.z;
            s3 = a0.w + a1.w + a2.w + a3.w;
        }
        if (grp == 1 && t < 192) {
            sh.p.ps[t][0] = s0; sh.p.ps[t][1] = s1;
            sh.p.ps[t][2] = s2; sh.p.ps[t][3] = s3;
        }
        __syncthreads();
        if (grp == 0 && t < 192) {
            float inv = 1.0f / (float)c;
            __hip_bfloat16* xr = xb + (size_t)bn * cH + t * 4;
            xr[0] = __float2bfloat16((s0 + sh.p.ps[t][0]) * inv);
            xr[1] = __float2bfloat16((s1 + sh.p.ps[t][1]) * inv);
            xr[2] = __float2bfloat16((s2 + sh.p.ps[t][2]) * inv);
            xr[3] = __float2bfloat16((s3 + sh.p.ps[t][3]) * inv);
        }
    } else {
        // ---------------- wconv: 2 tiles per block ----------------
        int sub = tid >> 8;                         // which tile
        int t   = tid & 255;
        int bi = (blockIdx.x - cM) * 2 + sub;       // 0..1151 = (12 x 12 x 8)
        int bx = bi % 12, by = (bi / 12) % 12, mat = bi / 144;
        int layer = mat >> 2, which = mat & 3;
        const float* W = (which == 0 ? Wq : which == 1 ? Wk : which == 2 ? Wv : Wo)
                         + (size_t)layer * cH * cH;
        int k0 = by * 64, n0 = bx * 64;
        int r = t >> 2, cb = (t & 3) * 16;
        #pragma unroll
        for (int u = 0; u < 4; ++u) {
            float4 w4 = *(const float4*)(W + (size_t)(k0 + r) * cH + n0 + cb + u * 4);
            sh.T[sub][r][cb + u * 4 + 0] = w4.x; sh.T[sub][r][cb + u * 4 + 1] = w4.y;
            sh.T[sub][r][cb + u * 4 + 2] = w4.z; sh.T[sub][r][cb + u * 4 + 3] = w4.w;
        }
        __syncthreads();
        // lane writes 16 bf16 = 32 B contiguous (two 16-B stores)
        int nn = t >> 2, kseg = (t & 3) * 16;
        __hip_bfloat16 tmp[16] __attribute__((aligned(16)));
        #pragma unroll
        for (int j = 0; j < 16; ++j)
            tmp[j] = __float2bfloat16(sh.T[sub][kseg + j][nn]);
        __hip_bfloat16* dst = wt + ((size_t)mat * cH + n0 + nn) * cH + k0 + kseg;
        *(bf16x8*)(dst)     = *(const bf16x8*)(tmp);
        *(bf16x8*)(dst + 8) = *(const bf16x8*)(tmp + 8);
    }
}

// ---------------------------------------------------------------------------
// 2) Fused qkv-GEMM + attention.  One block per (batch, head) = 96 blocks.
//    launch_bounds(256,1): 1 block/CU anyway (96 blocks on 256 CUs), so lift
//    the VGPR cap and let the 7-load/k-step pipeline live in registers.
//    Explicit next-k prefetch breaks the load->waitcnt->mfma serial chain.
// ---------------------------------------------------------------------------
struct AttnShared {
    float QP[cNS][cDH + 4];  // Q, later overlaid by P
    float Ks[cNS][cDH + 4];
    float Vt[cDH][cNS + 4];
};

__global__ __launch_bounds__(256, 1) void qkvattn_kernel(
    const __hip_bfloat16* __restrict__ x_bf,
    const __hip_bfloat16* __restrict__ wqkv,   // [3][H][H] bf16 (n-major)
    const float* __restrict__ bq, const float* __restrict__ bk,
    const float* __restrict__ bv,
    __hip_bfloat16* __restrict__ ctx_bf)
{
    __shared__ AttnShared sh;
    int tid = threadIdx.x;
    int lane = tid & 63, wave = tid >> 6;
    int l15 = lane & 15, q4 = lane >> 4;
    int b = blockIdx.x / cNH, hh = blockIdx.x % cNH;

    const __hip_bfloat16* Arow[4];
    #pragma unroll
    for (int m = 0; m < 4; ++m)
        Arow[m] = x_bf + (size_t)(b * 64 + m * 16 + l15) * cH + q4 * 8;
    const __hip_bfloat16* Brow[3];
    int cmat[3], cnt_[3];
    #pragma unroll
    for (int j = 0; j < 3; ++j) {
        int c = wave * 3 + j;
        cmat[j] = c >> 2; cnt_[j] = c & 3;
        Brow[j] = wqkv + (size_t)cmat[j] * cH * cH
                       + (size_t)(hh * 64 + cnt_[j] * 16 + l15) * cH + q4 * 8;
    }

    f32x4 acc[3][4];
    #pragma unroll
    for (int j = 0; j < 3; ++j)
        #pragma unroll
        for (int m = 0; m < 4; ++m) acc[j][m] = (f32x4){0.f, 0.f, 0.f, 0.f};

    // software-pipelined k-loop: prefetch k0+32 while MFMA on k0
    bf16x8 a[4], bb8[3], an[4], bn8[3];
    #pragma unroll
    for (int m = 0; m < 4; ++m) a[m] = *(const bf16x8*)(Arow[m]);
    #pragma unroll
    for (int j = 0; j < 3; ++j) bb8[j] = *(const bf16x8*)(Brow[j]);
    #pragma unroll
    for (int k0 = 0; k0 < cH; k0 += 32) {
        if (k0 + 32 < cH) {
            #pragma unroll
            for (int m = 0; m < 4; ++m) an[m] = *(const bf16x8*)(Arow[m] + k0 + 32);
            #pragma unroll
            for (int j = 0; j < 3; ++j) bn8[j] = *(const bf16x8*)(Brow[j] + k0 + 32);
        }
        #pragma unroll
        for (int j = 0; j < 3; ++j)
            #pragma unroll
            for (int m = 0; m < 4; ++m)
                acc[j][m] = __builtin_amdgcn_mfma_f32_16x16x32_bf16(a[m], bb8[j], acc[j][m], 0, 0, 0);
        #pragma unroll
        for (int m = 0; m < 4; ++m) a[m] = an[m];
        #pragma unroll
        for (int j = 0; j < 3; ++j) bb8[j] = bn8[j];
    }

    const float scale = 0.125f;  // 1/sqrt(64)
    #pragma unroll
    for (int j = 0; j < 3; ++j) {
        int mat = cmat[j], nt = cnt_[j];
        int col_d = nt * 16 + l15;
        int col_g = hh * 64 + col_d;
        float bias = (mat == 0 ? bq : mat == 1 ? bk : bv)[col_g];
        #pragma unroll
        for (int m = 0; m < 4; ++m) {
            #pragma unroll
            for (int r = 0; r < 4; ++r) {
                int row_s = m * 16 + q4 * 4 + r;
                float v = acc[j][m][r] + bias;
                if (mat == 0)      sh.QP[row_s][col_d] = v * scale;
                else if (mat == 1) sh.Ks[row_s][col_d] = v;
                else               sh.Vt[col_d][row_s] = v;
            }
        }
    }
    __syncthreads();

    int tx = tid & 15, ty = tid >> 4;  // 16x16 threads, 4x4 microtiles
    float accs[4][4] = {};
    for (int d = 0; d < cDH; d += 4) {
        float4 qv[4], kv[4];
        #pragma unroll
        for (int i = 0; i < 4; ++i) qv[i] = *(const float4*)&sh.QP[ty * 4 + i][d];
        #pragma unroll
        for (int j = 0; j < 4; ++j) kv[j] = *(const float4*)&sh.Ks[tx + j * 16][d];
        #pragma unroll
        for (int i = 0; i < 4; ++i)
            #pragma unroll
            for (int j = 0; j < 4; ++j)
                accs[i][j] += qv[i].x * kv[j].x + qv[i].y * kv[j].y +
                              qv[i].z * kv[j].z + qv[i].w * kv[j].w;
    }
    __syncthreads();   // all QK^T reads done before P overlays Q
    #pragma unroll
    for (int i = 0; i < 4; ++i)
        #pragma unroll
        for (int j = 0; j < 4; ++j)
            sh.QP[ty * 4 + i][tx + j * 16] = accs[i][j];
    __syncthreads();

    {   // softmax: row = tid>>2, 16 cols/thread, quad shuffle
        int row = tid >> 2, jq = tid & 3;
        float e[16];
        float m = -1e30f;
        #pragma unroll
        for (int c = 0; c < 16; ++c) { e[c] = sh.QP[row][jq * 16 + c]; m = fmaxf(m, e[c]); }
        m = fmaxf(m, __shfl_xor(m, 1));
        m = fmaxf(m, __shfl_xor(m, 2));
        float s = 0.f;
        #pragma unroll
        for (int c = 0; c < 16; ++c) { e[c] = __expf(e[c] - m); s += e[c]; }
        s += __shfl_xor(s, 1);
        s += __shfl_xor(s, 2);
        float inv = 1.0f / s;
        #pragma unroll
        for (int c = 0; c < 16; ++c) sh.QP[row][jq * 16 + c] = e[c] * inv;
    }
    __syncthreads();

    float acco[4][4] = {};
    for (int c = 0; c < cNS; c += 4) {
        float4 p4[4], vt4[4];
        #pragma unroll
        for (int i = 0; i < 4; ++i) p4[i] = *(const float4*)&sh.QP[ty * 4 + i][c];
        #pragma unroll
        for (int j = 0; j < 4; ++j) vt4[j] = *(const float4*)&sh.Vt[tx + j * 16][c];
        #pragma unroll
        for (int i = 0; i < 4; ++i)
            #pragma unroll
            for (int j = 0; j < 4; ++j)
                acco[i][j] += p4[i].x * vt4[j].x + p4[i].y * vt4[j].y +
                              p4[i].z * vt4[j].z + p4[i].w * vt4[j].w;
    }
    size_t base = ((size_t)b * cNS) * cH + hh * cDH;
    #pragma unroll
    for (int i = 0; i < 4; ++i)
        #pragma unroll
        for (int j = 0; j < 4; ++j)
            ctx_bf[base + (size_t)(ty * 4 + i) * cH + tx + j * 16] =
                __float2bfloat16(acco[i][j]);
}

// ---------------------------------------------------------------------------
// 3) O-GEMM + bias + GELU + in-block LayerNorm.  Grid = 32 blocks x 512 thr.
//    Each block owns 16 COMPLETE rows; wave w owns n-slice w*96 (6 MFMA
//    tiles -> acc 24 + frag 24 VGPR: fits, no load serialization; round-4's
//    12-tile/wave layout was register-starved at VGPR=60 -> 81 us).
//    Explicit next-k prefetch. Waves cover Wt disjointly (no dup reads).
//    LN is block-local (no fence, no extra dispatch); h stays in LDS.
// ---------------------------------------------------------------------------
__global__ __launch_bounds__(512, 1) void ogemm_ln_kernel(
    const __hip_bfloat16* __restrict__ A,      // ctx_bf [M][H]
    const __hip_bfloat16* __restrict__ Wt,     // [H][H] n-major
    const float* __restrict__ bias,
    const float* __restrict__ g, const float* __restrict__ bb,
    __hip_bfloat16* __restrict__ xb,           // LN out bf16 [M][H]
    float* __restrict__ outf)                  // LN out f32 (last layer) or null
{
    __shared__ unsigned short hs[16][776];     // h tile (bf16 bits), 24.3 KB
    int tid  = threadIdx.x;
    int lane = tid & 63;
    int wave = tid >> 6;
    int l15 = lane & 15, q4 = lane >> 4;
    int r0 = blockIdx.x * 16;
    int nb = wave * 96;                        // 6 n-tiles of 16

    const __hip_bfloat16* Arow = A  + (size_t)(r0 + l15) * cH + q4 * 8;
    const __hip_bfloat16* Wr   = Wt + (size_t)(nb + l15) * cH + q4 * 8;

    f32x4 acc[6];
    #pragma unroll
    for (int j = 0; j < 6; ++j) acc[j] = (f32x4){0.f, 0.f, 0.f, 0.f};

    bf16x8 a, bw[6], an, bn[6];
    a = *(const bf16x8*)(Arow);
    #pragma unroll
    for (int j = 0; j < 6; ++j) bw[j] = *(const bf16x8*)(Wr + (size_t)j * 16 * cH);
    #pragma unroll
    for (int k0 = 0; k0 < cH; k0 += 32) {
        if (k0 + 32 < cH) {
            an = *(const bf16x8*)(Arow + k0 + 32);
            #pragma unroll
            for (int j = 0; j < 6; ++j)
                bn[j] = *(const bf16x8*)(Wr + (size_t)j * 16 * cH + k0 + 32);
        }
        #pragma unroll
        for (int j = 0; j < 6; ++j)
            acc[j] = __builtin_amdgcn_mfma_f32_16x16x32_bf16(a, bw[j], acc[j], 0, 0, 0);
        a = an;
        #pragma unroll
        for (int j = 0; j < 6; ++j) bw[j] = bn[j];
    }

    // bias + GELU -> LDS (bf16 bits, matching baseline's bf16 h numerics)
    #pragma unroll
    for (int j = 0; j < 6; ++j) {
        int col = nb + j * 16 + l15;
        float bv = bias[col];
        #pragma unroll
        for (int r = 0; r < 4; ++r) {
            float v = acc[j][r] + bv;
            v = 0.5f * v * (1.0f + erff(v * 0.70710678118654752f));
            hs[q4 * 4 + r][col] = f2b(v);
        }
    }
    __syncthreads();

    // ---- in-block LN: wave handles rows wave*2, wave*2+1; 12 elems/lane ---
    float gv[12], bv2[12];
    {
        const float* gp = g  + lane * 12;
        const float* bp = bb + lane * 12;
        #pragma unroll
        for (int j = 0; j < 3; ++j) {
            float4 g4 = *(const float4*)(gp + j * 4);
            float4 b4 = *(const float4*)(bp + j * 4);
            gv[j * 4 + 0] = g4.x; gv[j * 4 + 1] = g4.y;
            gv[j * 4 + 2] = g4.z; gv[j * 4 + 3] = g4.w;
            bv2[j * 4 + 0] = b4.x; bv2[j * 4 + 1] = b4.y;
            bv2[j * 4 + 2] = b4.z; bv2[j * 4 + 3] = b4.w;
        }
    }
    #pragma unroll
    for (int rr = 0; rr < 2; ++rr) {
        int lrow = wave * 2 + rr;
        int grow = r0 + lrow;
        const unsigned short* hr = &hs[lrow][lane * 12];
        float v[12];
        #pragma unroll
        for (int j = 0; j < 3; ++j) {
            u16x4 q = *(const u16x4*)(hr + j * 4);
            v[j * 4 + 0] = b2f(q[0]); v[j * 4 + 1] = b2f(q[1]);
            v[j * 4 + 2] = b2f(q[2]); v[j * 4 + 3] = b2f(q[3]);
        }
        float s = 0.f;
        #pragma unroll
        for (int j = 0; j < 12; ++j) s += v[j];
        #pragma unroll
        for (int o = 32; o; o >>= 1) s += __shfl_xor(s, o);
        float mu = s * (1.0f / 768.0f);
        float ss = 0.f;
        #pragma unroll
        for (int j = 0; j < 12; ++j) { v[j] -= mu; ss += v[j] * v[j]; }
        #pragma unroll
        for (int o = 32; o; o >>= 1) ss += __shfl_xor(ss, o);
        float var = ss * (1.0f / 768.0f);
        float inv = rsqrtf(var + 1e-12f);
        float o12[12];
        #pragma unroll
        for (int j = 0; j < 12; ++j) o12[j] = v[j] * inv * gv[j] + bv2[j];

        unsigned short* xr = (unsigned short*)(xb + (size_t)grow * cH) + lane * 12;
        #pragma unroll
        for (int j = 0; j < 3; ++j) {
            u16x4 q;
            q[0] = f2b(o12[j * 4 + 0]); q[1] = f2b(o12[j * 4 + 1]);
            q[2] = f2b(o12[j * 4 + 2]); q[3] = f2b(o12[j * 4 + 3]);
            *(u16x4*)(xr + j * 4) = q;
        }
        if (outf) {
            float* orow = outf + (size_t)grow * cH + lane * 12;
            #pragma unroll
            for (int j = 0; j < 3; ++j) {
                float4 o4 = { o12[j * 4 + 0], o12[j * 4 + 1],
                              o12[j * 4 + 2], o12[j * 4 + 3] };
                *(float4*)(orow + j * 4) = o4;
            }
        }
    }
}

// ---------------------------------------------------------------------------
extern "C" void kernel_launch(void* const* d_in, const int* in_sizes, int n_in,
                              void* d_out, int out_size, void* d_ws, size_t ws_size,
                              hipStream_t stream) {
    const int*   sent_ind = (const int*)d_in[0];
    const float* start    = (const float*)d_in[1];
    const float* Wq = (const float*)d_in[2];
    const float* bq = (const float*)d_in[3];
    const float* Wk = (const float*)d_in[4];
    const float* bk = (const float*)d_in[5];
    const float* Wv = (const float*)d_in[6];
    const float* bv = (const float*)d_in[7];
    const float* Wo = (const float*)d_in[8];
    const float* bo = (const float*)d_in[9];
    const float* ln_g = (const float*)d_in[10];
    const float* ln_b = (const float*)d_in[11];
    float* out = (float*)d_out;

    char* w = (char*)d_ws;
    __hip_bfloat16* wt     = (__hip_bfloat16*)w;                          // 8*H*H bf16
    __hip_bfloat16* x_bf   = (__hip_bfloat16*)(w + 9437184);              // M*H bf16
    __hip_bfloat16* ctx_bf = (__hip_bfloat16*)(w + 9437184 + 786432);     // M*H bf16

    prep_kernel<<<cM + 576, 512, 0, stream>>>(sent_ind, start, x_bf,
                                              Wq, Wk, Wv, Wo, wt);

    for (int i = 0; i < cL; ++i) {
        const __hip_bfloat16* wqkv = wt + (size_t)(i * 4) * cH * cH;     // q,k,v contiguous
        const __hip_bfloat16* wto  = wt + (size_t)(i * 4 + 3) * cH * cH;
        qkvattn_kernel<<<cB * cNH, 256, 0, stream>>>(
            x_bf, wqkv, bq + (size_t)i * cH, bk + (size_t)i * cH, bv + (size_t)i * cH,
            ctx_bf);
        ogemm_ln_kernel<<<32, 512, 0, stream>>>(
            ctx_bf, wto, bo + (size_t)i * cH,
            ln_g + (size_t)i * cH, ln_b + (size_t)i * cH,
            x_bf, (i == cL - 1) ? out : nullptr);
    }
}